// Round 3
// baseline (448.851 us; speedup 1.0000x reference)
//
#include <hip/hip_runtime.h>
#include <hip/hip_bf16.h>

#define BN 16
#define NN 2048

// float32(2*pi) and float32(pi) — match JAX/np f32 promotion of python floats
#define P_F  6.28318530717958647692f
#define HP_F 3.14159265358979323846f

// np.mod semantics for floats (positive divisor): trunc-rem, add divisor if neg
__device__ __forceinline__ float pmod(float x) {
    float r = fmodf(x, P_F);
    return (r < 0.0f) ? r + P_F : r;
}

// fast direct-form adjacency (big output pass only; value tol is 8.75e-2)
__device__ __forceinline__ float adjval(float xi, float a1, float a2,
                                        float xj, float b1, float b2) {
    float dx = xi - xj;
    float t  = dx * dx;
    float u  = a1 - b1;
    float v  = a2 - b2;
    float d1 = fmaf(u, u, t);
    float d2 = fmaf(v, v, t);
    return __expf(-fminf(d1, d2));
}

// ---------------- Pass 1: degrees, bit-matching numpy ----------------
// Elements: np einsum SOP order, contract off, f64 exp -> f32 (cr rounding).
// Row sum: numpy pairwise_sum replicated EXACTLY:
//   2048 -> 16 chunks of 128 (contiguous); base case = 8 interleaved f32
//   accumulators + ((r0+r1)+(r2+r3))+((r4+r5)+(r6+r7)); chunk sums combined
//   in numpy's binary-split tree == shfl_xor butterfly masks 1,2,4,8.
// 16 rows/block, 16 lanes/row; grid = BN * (NN/16).
__global__ __launch_bounds__(256) void k_degree(const float* __restrict__ phi,
                                                const float* __restrict__ eta,
                                                float* __restrict__ degree) {
#pragma clang fp contract(off)
    int blk = blockIdx.x;
    int b   = blk >> 7;            // / (NN/16)
    int r0  = (blk & 127) << 4;    // * 16

    __shared__ float se[NN], sp1[NN], sp2[NN], sn1[NN], sn2[NN];  // 40 KB
    const float* pb = phi + (size_t)b * NN;
    const float* eb = eta + (size_t)b * NN;
    for (int j = threadIdx.x; j < NN; j += 256) {
        float p  = pb[j];
        float x  = eb[j];
        float p1 = pmod(p);
        float p2 = pmod(p + HP_F);
        se[j]  = x;
        sp1[j] = p1;
        sp2[j] = p2;
        sn1[j] = x * x + p1 * p1;   // np sum over d: eta^2 + phi^2
        sn2[j] = x * x + p2 * p2;
    }
    __syncthreads();

    int row16  = threadIdx.x >> 4;   // 0..15
    int lane16 = threadIdx.x & 15;   // 0..15
    int i = r0 + row16;

    float xi  = se[i],  p1i = sp1[i], p2i = sp2[i];
    float n1i = sn1[i], n2i = sn2[i];

    int jbase = lane16 * 128;        // this lane's contiguous chunk

    // element value, np op order: dot = e*e + p*p (SOP, no FMA);
    // d = (n_i + n_j) - 2*dot; adj = exp(-d) at f64 accuracy, f32-rounded
    auto elem = [&](int j) -> float {
        float me   = xi * se[j];
        float dot1 = me + p1i * sp1[j];
        float dot2 = me + p2i * sp2[j];
        float d1   = (n1i + sn1[j]) - 2.0f * dot1;
        float d2   = (n2i + sn2[j]) - 2.0f * dot2;
        float dmin = fminf(d1, d2);
        return (float)exp(-(double)dmin);
    };

    // numpy base case over 128 contiguous elements
    float r[8];
    #pragma unroll
    for (int t = 0; t < 8; ++t) r[t] = elem(jbase + t);
    for (int i8 = 8; i8 < 128; i8 += 8) {
        #pragma unroll
        for (int t = 0; t < 8; ++t) r[t] = r[t] + elem(jbase + i8 + t);
    }
    float rr = ((r[0] + r[1]) + (r[2] + r[3])) + ((r[4] + r[5]) + (r[6] + r[7]));

    // numpy binary-split tree over the 16 chunk sums (masks 1,2,4,8;
    // commutativity makes every lane's partial bitwise-identical to np's)
    #pragma unroll
    for (int m = 1; m <= 8; m <<= 1) {
        rr = rr + __shfl_xor(rr, m, 64);
    }
    if (lane16 == 0) degree[(size_t)b * NN + i] = rr;
}

// ---------------- Pass 2: per-batch bitonic argsort (descending, stable) ----
// f32 keys (np's degree dtype); strict total order via index tie-break
// == stable argsort(-degree).
__global__ __launch_bounds__(1024) void k_sort(const float* __restrict__ degree,
                                               int* __restrict__ order) {
    int b = blockIdx.x;
    __shared__ float key[NN];
    __shared__ int   idx[NN];
    for (int i = threadIdx.x; i < NN; i += 1024) {
        key[i] = degree[(size_t)b * NN + i];
        idx[i] = i;
    }
    __syncthreads();

    for (int k = 2; k <= NN; k <<= 1) {
        for (int j = k >> 1; j > 0; j >>= 1) {
            for (int i = threadIdx.x; i < NN; i += 1024) {
                int ixj = i ^ j;
                if (ixj > i) {
                    float ka = key[i], kb = key[ixj];
                    int   ia = idx[i], ib = idx[ixj];
                    bool before = (ka > kb) || (ka == kb && ia < ib);
                    bool revSeg = ((i & k) != 0);
                    bool doSwap = revSeg ? before : !before;
                    if (doSwap) {
                        key[i] = kb; key[ixj] = ka;
                        idx[i] = ib; idx[ixj] = ia;
                    }
                }
            }
            __syncthreads();
        }
    }
    for (int i = threadIdx.x; i < NN; i += 1024) {
        order[(size_t)b * NN + i] = idx[i];
    }
}

// ---------------- Pass 3: permute per-node vectors into d_out --------------
__global__ __launch_bounds__(256) void k_perm(const float* __restrict__ e,
                                              const float* __restrict__ phi,
                                              const float* __restrict__ eta,
                                              const int* __restrict__ order,
                                              float* __restrict__ out_e,
                                              float* __restrict__ out_phi,
                                              float* __restrict__ out_eta) {
    int t = blockIdx.x * 256 + threadIdx.x;  // < BN*NN
    int b = t / NN;
    int o = order[t];
    size_t src = (size_t)b * NN + o;
    out_e[t]   = e[src];
    out_phi[t] = phi[src];
    out_eta[t] = eta[src];
}

// ---------------- Pass 4: adjacency recomputed in permuted order -----------
// adj is a symmetric function of node values: adj_o[i][j] = f(nd[o_i],nd[o_j])
#define ROWS 8
__global__ __launch_bounds__(256) void k_adj(const float* __restrict__ phi_o,
                                             const float* __restrict__ eta_o,
                                             float* __restrict__ adj) {
    int blk = blockIdx.x;
    int b   = blk / (NN / ROWS);
    int r0  = (blk % (NN / ROWS)) * ROWS;

    __shared__ float sx[NN], s1[NN], s2[NN];
    const float* pb = phi_o + (size_t)b * NN;
    const float* eb = eta_o + (size_t)b * NN;
    for (int j = threadIdx.x; j < NN; j += 256) {
        float p = pb[j];
        sx[j] = eb[j];
        s1[j] = pmod(p);
        s2[j] = pmod(p + HP_F);
    }
    __syncthreads();

    float* base = adj + ((size_t)b * NN + r0) * NN;
    for (int r = 0; r < ROWS; ++r) {
        int i = r0 + r;
        float xi = sx[i], a1 = s1[i], a2 = s2[i];
        #pragma unroll
        for (int p = 0; p < 2; ++p) {
            int j0 = p * 1024 + threadIdx.x * 4;
            float4 xv = *reinterpret_cast<const float4*>(&sx[j0]);
            float4 y1 = *reinterpret_cast<const float4*>(&s1[j0]);
            float4 y2 = *reinterpret_cast<const float4*>(&s2[j0]);
            float4 o;
            o.x = adjval(xi, a1, a2, xv.x, y1.x, y2.x);
            o.y = adjval(xi, a1, a2, xv.y, y1.y, y2.y);
            o.z = adjval(xi, a1, a2, xv.z, y1.z, y2.z);
            o.w = adjval(xi, a1, a2, xv.w, y1.w, y2.w);
            *reinterpret_cast<float4*>(&base[(size_t)r * NN + j0]) = o;
        }
    }
}

extern "C" void kernel_launch(void* const* d_in, const int* in_sizes, int n_in,
                              void* d_out, int out_size, void* d_ws, size_t ws_size,
                              hipStream_t stream) {
    const float* e   = (const float*)d_in[0];
    const float* phi = (const float*)d_in[1];
    const float* eta = (const float*)d_in[2];

    float* adj     = (float*)d_out;
    float* out_e   = adj + (size_t)BN * NN * NN;
    float* out_phi = out_e + (size_t)BN * NN;
    float* out_eta = out_phi + (size_t)BN * NN;

    float* degree = (float*)d_ws;                                           // 128 KB
    int*   order  = (int*)((char*)d_ws + (size_t)BN * NN * sizeof(float));  // 128 KB

    k_degree<<<BN * (NN / 16), 256, 0, stream>>>(phi, eta, degree);
    k_sort<<<BN, 1024, 0, stream>>>(degree, order);
    k_perm<<<(BN * NN) / 256, 256, 0, stream>>>(e, phi, eta, order,
                                                out_e, out_phi, out_eta);
    k_adj<<<BN * (NN / ROWS), 256, 0, stream>>>(out_phi, out_eta, adj);
}

// Round 4
// 400.183 us; speedup vs baseline: 1.1216x; 1.1216x over previous
//
#include <hip/hip_runtime.h>
#include <hip/hip_bf16.h>

#define BN 16
#define NN 2048

// float32(2*pi) and float32(pi) — match JAX/np f32 promotion of python floats
#define P_F  6.28318530717958647692f
#define HP_F 3.14159265358979323846f

// padded LDS index: stride 129 floats per 128-chunk -> conflict-free chunk reads
#define PIDX(j) ((j) + ((j) >> 7))
#define PN (NN + 16)

// np.mod semantics for floats (positive divisor): trunc-rem, add divisor if neg
__device__ __forceinline__ float pmod(float x) {
    float r = fmodf(x, P_F);
    return (r < 0.0f) ? r + P_F : r;
}

// fast direct-form adjacency (big output pass only; value tol is 8.75e-2)
__device__ __forceinline__ float adjval(float xi, float a1, float a2,
                                        float xj, float b1, float b2) {
    float dx = xi - xj;
    float t  = dx * dx;
    float u  = a1 - b1;
    float v  = a2 - b2;
    float d1 = fmaf(u, u, t);
    float d2 = fmaf(v, v, t);
    return __expf(-fminf(d1, d2));
}

// Branch-free f64 exp, rel err <= ~1e-14: f32-rounded result matches libm
// exp(double) except ~1e-7 fraction of inputs (1 f32 ulp) — far below the
// degree-ordering noise already tolerated. x in [-160, 0].
__device__ __forceinline__ double expd_fast(double x) {
    const double L2E   = 1.44269504088896338700e+00;
    const double LN2HI = 6.93147180369123816490e-01;
    const double LN2LO = 1.90821492927058770002e-10;
    double n  = rint(x * L2E);
    double r  = fma(n, -LN2HI, x);
    r         = fma(n, -LN2LO, r);
    double h  = 2.5052108385441720e-08;        // 1/11!
    h = fma(h, r, 2.7557319223985888e-07);     // 1/10!
    h = fma(h, r, 2.7557319223985893e-06);     // 1/9!
    h = fma(h, r, 2.4801587301587302e-05);     // 1/8!
    h = fma(h, r, 1.9841269841269841e-04);     // 1/7!
    h = fma(h, r, 1.3888888888888889e-03);     // 1/6!
    h = fma(h, r, 8.3333333333333332e-03);     // 1/5!
    h = fma(h, r, 4.1666666666666664e-02);     // 1/4!
    h = fma(h, r, 1.6666666666666666e-01);     // 1/3!
    h = fma(h, r, 0.5);                        // 1/2!
    double q = fma(h, r, 1.0);
    double e = fma(q, r, 1.0);
    long long ll = (long long)n;
    double s = __longlong_as_double((ll + 1023) << 52);   // 2^n (n >= -1000)
    return e * s;
}

// ---------------- Pass 1: degrees, bit-matching numpy ----------------
// Elements: np einsum SOP order (contract off), f64 exp -> f32.
// Row sum: numpy pairwise_sum EXACT tree: 16 contiguous chunks of 128,
// base case = 8 interleaved accumulators + ((r0+r1)+(r2+r3))+((r4+r5)+(r6+r7)),
// chunk sums combined by binary-split tree == shfl_xor butterfly 1,2,4,8.
// 16 rows/block, 16 lanes/row; grid = BN * (NN/16).
__global__ __launch_bounds__(256) void k_degree(const float* __restrict__ phi,
                                                const float* __restrict__ eta,
                                                float* __restrict__ degree) {
#pragma clang fp contract(off)
    int blk = blockIdx.x;
    int b   = blk >> 7;            // / (NN/16)
    int r0  = (blk & 127) << 4;    // * 16

    __shared__ float se[PN], sp1[PN], sp2[PN], sn1[PN], sn2[PN];  // ~41 KB
    const float* pb = phi + (size_t)b * NN;
    const float* eb = eta + (size_t)b * NN;
    for (int j = threadIdx.x; j < NN; j += 256) {
        float p  = pb[j];
        float x  = eb[j];
        float p1 = pmod(p);
        float p2 = pmod(p + HP_F);
        int jj = PIDX(j);
        se[jj]  = x;
        sp1[jj] = p1;
        sp2[jj] = p2;
        sn1[jj] = x * x + p1 * p1;   // np sqnorm op order: eta^2 + phi^2
        sn2[jj] = x * x + p2 * p2;
    }
    __syncthreads();

    int row16  = threadIdx.x >> 4;   // 0..15
    int lane16 = threadIdx.x & 15;   // 0..15
    int i  = r0 + row16;
    int ii = PIDX(i);

    float xi  = se[ii],  p1i = sp1[ii], p2i = sp2[ii];
    float n1i = sn1[ii], n2i = sn2[ii];

    int jbase = lane16 * 129;        // padded base of this lane's 128-chunk

    auto elem = [&](int jj) -> float {
        float me   = xi * se[jj];
        float dot1 = me + p1i * sp1[jj];
        float dot2 = me + p2i * sp2[jj];
        float d1   = (n1i + sn1[jj]) - 2.0f * dot1;
        float d2   = (n2i + sn2[jj]) - 2.0f * dot2;
        float dmin = fminf(d1, d2);
        return (float)expd_fast(-(double)dmin);
    };

    // numpy base case over the 128 contiguous elements of this chunk
    float r[8];
    #pragma unroll
    for (int t = 0; t < 8; ++t) r[t] = elem(jbase + t);
    #pragma unroll 2
    for (int i8 = 8; i8 < 128; i8 += 8) {
        #pragma unroll
        for (int t = 0; t < 8; ++t) r[t] = r[t] + elem(jbase + i8 + t);
    }
    float rr = ((r[0] + r[1]) + (r[2] + r[3])) + ((r[4] + r[5]) + (r[6] + r[7]));

    // numpy binary-split tree over 16 chunk sums (butterfly; commutativity
    // makes every lane's partial bitwise-identical to np's tree)
    #pragma unroll
    for (int m = 1; m <= 8; m <<= 1) {
        rr = rr + __shfl_xor(rr, m, 64);
    }
    if (lane16 == 0) degree[(size_t)b * NN + i] = rr;
}

// ---------------- Pass 2: O(N^2) rank + scatter (replaces sort+perm) -------
// rank[i] = #{j: dj>di} + #{j<i: dj==di}  == position in stable argsort(-deg).
// Scatter the per-node vectors directly: out[rank] = in[i]. No order array.
__global__ __launch_bounds__(256) void k_rank(const float* __restrict__ degree,
                                              const float* __restrict__ e,
                                              const float* __restrict__ phi,
                                              const float* __restrict__ eta,
                                              float* __restrict__ out_e,
                                              float* __restrict__ out_phi,
                                              float* __restrict__ out_eta) {
    int blk = blockIdx.x;
    int b   = blk >> 3;            // / 8
    int r0  = (blk & 7) << 8;      // * 256
    int i   = r0 + threadIdx.x;

    __shared__ float sdeg[NN];     // 8 KB
    const float* db = degree + (size_t)b * NN;
    for (int j = threadIdx.x; j < NN; j += 256) sdeg[j] = db[j];
    __syncthreads();

    float di = sdeg[i];
    int c0 = 0, c1 = 0, c2 = 0, c3 = 0;
    #pragma unroll 4
    for (int j = 0; j < NN; j += 4) {
        float d0 = sdeg[j], d1v = sdeg[j + 1], d2v = sdeg[j + 2], d3v = sdeg[j + 3];
        c0 += (d0  > di) || (d0  == di && (j    ) < i);
        c1 += (d1v > di) || (d1v == di && (j + 1) < i);
        c2 += (d2v > di) || (d2v == di && (j + 2) < i);
        c3 += (d3v > di) || (d3v == di && (j + 3) < i);
    }
    int rank = (c0 + c1) + (c2 + c3);

    size_t src = (size_t)b * NN + i;
    size_t dst = (size_t)b * NN + rank;
    out_e[dst]   = e[src];
    out_phi[dst] = phi[src];
    out_eta[dst] = eta[src];
}

// ---------------- Pass 3: adjacency recomputed in permuted order -----------
// adj is a symmetric function of node values: adj_o[i][j] = f(nd[o_i],nd[o_j])
#define ROWS 8
__global__ __launch_bounds__(256) void k_adj(const float* __restrict__ phi_o,
                                             const float* __restrict__ eta_o,
                                             float* __restrict__ adj) {
    int blk = blockIdx.x;
    int b   = blk / (NN / ROWS);
    int r0  = (blk % (NN / ROWS)) * ROWS;

    __shared__ float sx[NN], s1[NN], s2[NN];   // 24 KB
    const float* pb = phi_o + (size_t)b * NN;
    const float* eb = eta_o + (size_t)b * NN;
    for (int j = threadIdx.x; j < NN; j += 256) {
        float p = pb[j];
        sx[j] = eb[j];
        s1[j] = pmod(p);
        s2[j] = pmod(p + HP_F);
    }
    __syncthreads();

    float* base = adj + ((size_t)b * NN + r0) * NN;
    for (int r = 0; r < ROWS; ++r) {
        int i = r0 + r;
        float xi = sx[i], a1 = s1[i], a2 = s2[i];
        #pragma unroll
        for (int p = 0; p < 2; ++p) {
            int j0 = p * 1024 + threadIdx.x * 4;
            float4 xv = *reinterpret_cast<const float4*>(&sx[j0]);
            float4 y1 = *reinterpret_cast<const float4*>(&s1[j0]);
            float4 y2 = *reinterpret_cast<const float4*>(&s2[j0]);
            float4 o;
            o.x = adjval(xi, a1, a2, xv.x, y1.x, y2.x);
            o.y = adjval(xi, a1, a2, xv.y, y1.y, y2.y);
            o.z = adjval(xi, a1, a2, xv.z, y1.z, y2.z);
            o.w = adjval(xi, a1, a2, xv.w, y1.w, y2.w);
            *reinterpret_cast<float4*>(&base[(size_t)r * NN + j0]) = o;
        }
    }
}

extern "C" void kernel_launch(void* const* d_in, const int* in_sizes, int n_in,
                              void* d_out, int out_size, void* d_ws, size_t ws_size,
                              hipStream_t stream) {
    const float* e   = (const float*)d_in[0];
    const float* phi = (const float*)d_in[1];
    const float* eta = (const float*)d_in[2];

    float* adj     = (float*)d_out;
    float* out_e   = adj + (size_t)BN * NN * NN;
    float* out_phi = out_e + (size_t)BN * NN;
    float* out_eta = out_phi + (size_t)BN * NN;

    float* degree = (float*)d_ws;   // 128 KB scratch

    k_degree<<<BN * (NN / 16), 256, 0, stream>>>(phi, eta, degree);
    k_rank<<<BN * 8, 256, 0, stream>>>(degree, e, phi, eta,
                                       out_e, out_phi, out_eta);
    k_adj<<<BN * (NN / ROWS), 256, 0, stream>>>(out_phi, out_eta, adj);
}

// Round 7
// 393.993 us; speedup vs baseline: 1.1392x; 1.0157x over previous
//
#include <hip/hip_runtime.h>
#include <hip/hip_bf16.h>

#define BN 16
#define NN 2048

// float32(2*pi) and float32(pi) — match JAX/np f32 promotion of python floats
#define P_F  6.28318530717958647692f
#define HP_F 3.14159265358979323846f

// padded index: +1 slot per 128-chunk -> per-chunk lane reads spread banks
#define PIDX(j) ((j) + ((j) >> 7))
#define PN (NN + 16)

// native 4-float vector for nontemporal builtin (HIP float4 is a class)
typedef float float4n __attribute__((ext_vector_type(4)));

// np.mod semantics for floats (positive divisor): trunc-rem, add divisor if neg
__device__ __forceinline__ float pmod(float x) {
    float r = fmodf(x, P_F);
    return (r < 0.0f) ? r + P_F : r;
}

// fast direct-form adjacency (big output pass only; value tol is 8.75e-2)
__device__ __forceinline__ float adjval(float xi, float a1, float a2,
                                        float xj, float b1, float b2) {
    float dx = xi - xj;
    float t  = dx * dx;
    float u  = a1 - b1;
    float v  = a2 - b2;
    float d1 = fmaf(u, u, t);
    float d2 = fmaf(v, v, t);
    return __expf(-fminf(d1, d2));
}

// Branch-free f64 exp, deg-9 Taylor after Cody-Waite; rel err ~7e-12.
// f32-rounded result matches correctly-rounded except ~1e-4 of inputs by
// 1 f32 ulp — same noise scale as numpy's own SIMD exp. x in [-320, 0].
__device__ __forceinline__ double expd_fast(double x) {
    const double L2E   = 1.44269504088896338700e+00;
    const double LN2HI = 6.93147180369123816490e-01;
    const double LN2LO = 1.90821492927058770002e-10;
    double n  = rint(x * L2E);
    double r  = fma(n, -LN2HI, x);
    r         = fma(n, -LN2LO, r);
    double h  = 2.7557319223985893e-06;        // 1/9!
    h = fma(h, r, 2.4801587301587302e-05);     // 1/8!
    h = fma(h, r, 1.9841269841269841e-04);     // 1/7!
    h = fma(h, r, 1.3888888888888889e-03);     // 1/6!
    h = fma(h, r, 8.3333333333333332e-03);     // 1/5!
    h = fma(h, r, 4.1666666666666664e-02);     // 1/4!
    h = fma(h, r, 1.6666666666666666e-01);     // 1/3!
    h = fma(h, r, 0.5);                        // 1/2!
    double q = fma(h, r, 1.0);
    double e = fma(q, r, 1.0);
    long long ll = (long long)n;
    double s = __longlong_as_double((ll + 1023) << 52);   // 2^n
    return e * s;
}

// ---------------- Pass 1: degrees, bit-matching numpy ----------------
// Elements: np einsum SOP order (contract off), f64 exp -> f32.
// Row sum: numpy pairwise_sum EXACT tree (16 chunks of 128, 8-accumulator
// base case, binary-split combine == shfl_xor butterfly 1,2,4,8).
// LDS packed float4 {e, p1, p2, n1}; n2 recomputed per element with the
// identical np op order (deterministic rounding -> bit-identical).
__global__ __launch_bounds__(256) void k_degree(const float* __restrict__ phi,
                                                const float* __restrict__ eta,
                                                float* __restrict__ degree) {
#pragma clang fp contract(off)
    int blk = blockIdx.x;
    int b   = blk >> 7;            // / (NN/16)
    int r0  = (blk & 127) << 4;    // * 16

    __shared__ float4 spk[PN];     // 33 KB: {e, p1, p2, n1}
    const float* pb = phi + (size_t)b * NN;
    const float* eb = eta + (size_t)b * NN;
    for (int j = threadIdx.x; j < NN; j += 256) {
        float p  = pb[j];
        float x  = eb[j];
        float p1 = pmod(p);
        float p2 = pmod(p + HP_F);
        float n1 = x * x + p1 * p1;   // np sqnorm op order: eta^2 + phi^2
        spk[PIDX(j)] = make_float4(x, p1, p2, n1);
    }
    __syncthreads();

    int row16  = threadIdx.x >> 4;   // 0..15
    int lane16 = threadIdx.x & 15;   // 0..15
    int i = r0 + row16;

    float4 qi = spk[PIDX(i)];
    float xi  = qi.x, p1i = qi.y, p2i = qi.z, n1i = qi.w;
    float n2i = xi * xi + p2i * p2i;          // np op order

    int jbase = lane16 * 129;        // padded base of this lane's 128-chunk

    auto elem = [&](int jj) -> float {
        float4 q   = spk[jj];
        float me   = xi * q.x;
        float dot1 = me + p1i * q.y;
        float dot2 = me + p2i * q.z;
        float t    = q.x * q.x;
        float v    = q.z * q.z;
        float n2j  = t + v;                   // np op order
        float d1   = (n1i + q.w) - 2.0f * dot1;
        float d2   = (n2i + n2j) - 2.0f * dot2;
        float dmin = fminf(d1, d2);
        return (float)expd_fast(-(double)dmin);
    };

    // numpy base case over the 128 contiguous elements of this chunk
    float r[8];
    #pragma unroll
    for (int t = 0; t < 8; ++t) r[t] = elem(jbase + t);
    #pragma unroll 2
    for (int i8 = 8; i8 < 128; i8 += 8) {
        #pragma unroll
        for (int t = 0; t < 8; ++t) r[t] = r[t] + elem(jbase + i8 + t);
    }
    float rr = ((r[0] + r[1]) + (r[2] + r[3])) + ((r[4] + r[5]) + (r[6] + r[7]));

    // numpy binary-split tree over 16 chunk sums (butterfly; commutativity
    // makes every lane's partial bitwise-identical to np's tree)
    #pragma unroll
    for (int m = 1; m <= 8; m <<= 1) {
        rr = rr + __shfl_xor(rr, m, 64);
    }
    if (lane16 == 0) degree[(size_t)b * NN + i] = rr;
}

// ---------------- Pass 2: O(N^2) rank + scatter ----------------------------
// rank[i] = #{j: dj>di} + #{j<i: dj==di}  == position in stable argsort(-deg).
__global__ __launch_bounds__(256) void k_rank(const float* __restrict__ degree,
                                              const float* __restrict__ e,
                                              const float* __restrict__ phi,
                                              const float* __restrict__ eta,
                                              float* __restrict__ out_e,
                                              float* __restrict__ out_phi,
                                              float* __restrict__ out_eta) {
    int blk = blockIdx.x;
    int b   = blk >> 3;            // / 8
    int r0  = (blk & 7) << 8;      // * 256
    int i   = r0 + threadIdx.x;

    __shared__ float sdeg[NN];     // 8 KB
    const float* db = degree + (size_t)b * NN;
    for (int j = threadIdx.x; j < NN; j += 256) sdeg[j] = db[j];
    __syncthreads();

    float di = sdeg[i];
    int c0 = 0, c1 = 0, c2 = 0, c3 = 0;
    #pragma unroll 4
    for (int j = 0; j < NN; j += 4) {
        float4 d4 = *reinterpret_cast<const float4*>(&sdeg[j]);  // uniform addr
        c0 += (d4.x > di) || (d4.x == di && (j    ) < i);
        c1 += (d4.y > di) || (d4.y == di && (j + 1) < i);
        c2 += (d4.z > di) || (d4.z == di && (j + 2) < i);
        c3 += (d4.w > di) || (d4.w == di && (j + 3) < i);
    }
    int rank = (c0 + c1) + (c2 + c3);

    size_t src = (size_t)b * NN + i;
    size_t dst = (size_t)b * NN + rank;
    out_e[dst]   = e[src];
    out_phi[dst] = phi[src];
    out_eta[dst] = eta[src];
}

// ---------------- Pass 3: adjacency recomputed in permuted order -----------
// adj is a symmetric function of node values: adj_o[i][j] = f(nd[o_i],nd[o_j]).
// j-side float4 loads hoisted out of the row loop (read once per 16 rows).
#define ROWS 16
__global__ __launch_bounds__(256) void k_adj(const float* __restrict__ phi_o,
                                             const float* __restrict__ eta_o,
                                             float* __restrict__ adj) {
    int blk = blockIdx.x;
    int b   = blk >> 7;            // / (NN/ROWS)
    int r0  = (blk & 127) << 4;    // * ROWS

    __shared__ float sx[NN], s1[NN], s2[NN];   // 24 KB
    const float* pb = phi_o + (size_t)b * NN;
    const float* eb = eta_o + (size_t)b * NN;
    for (int j = threadIdx.x; j < NN; j += 256) {
        float p = pb[j];
        sx[j] = eb[j];
        s1[j] = pmod(p);
        s2[j] = pmod(p + HP_F);
    }
    __syncthreads();

    // row-side constants into registers (static indices after unroll)
    float xi[ROWS], a1[ROWS], a2[ROWS];
    #pragma unroll
    for (int r = 0; r < ROWS; ++r) {
        xi[r] = sx[r0 + r];
        a1[r] = s1[r0 + r];
        a2[r] = s2[r0 + r];
    }

    float* base = adj + ((size_t)b * NN + r0) * NN;
    #pragma unroll
    for (int p = 0; p < 2; ++p) {
        int j0 = p * 1024 + threadIdx.x * 4;
        float4 xv = *reinterpret_cast<const float4*>(&sx[j0]);
        float4 y1 = *reinterpret_cast<const float4*>(&s1[j0]);
        float4 y2 = *reinterpret_cast<const float4*>(&s2[j0]);
        #pragma unroll
        for (int r = 0; r < ROWS; ++r) {
            float4n o;
            o.x = adjval(xi[r], a1[r], a2[r], xv.x, y1.x, y2.x);
            o.y = adjval(xi[r], a1[r], a2[r], xv.y, y1.y, y2.y);
            o.z = adjval(xi[r], a1[r], a2[r], xv.z, y1.z, y2.z);
            o.w = adjval(xi[r], a1[r], a2[r], xv.w, y1.w, y2.w);
            __builtin_nontemporal_store(o,
                reinterpret_cast<float4n*>(&base[(size_t)r * NN + j0]));
        }
    }
}

extern "C" void kernel_launch(void* const* d_in, const int* in_sizes, int n_in,
                              void* d_out, int out_size, void* d_ws, size_t ws_size,
                              hipStream_t stream) {
    const float* e   = (const float*)d_in[0];
    const float* phi = (const float*)d_in[1];
    const float* eta = (const float*)d_in[2];

    float* adj     = (float*)d_out;
    float* out_e   = adj + (size_t)BN * NN * NN;
    float* out_phi = out_e + (size_t)BN * NN;
    float* out_eta = out_phi + (size_t)BN * NN;

    float* degree = (float*)d_ws;   // 128 KB scratch

    k_degree<<<BN * (NN / 16), 256, 0, stream>>>(phi, eta, degree);
    k_rank<<<BN * 8, 256, 0, stream>>>(degree, e, phi, eta,
                                       out_e, out_phi, out_eta);
    k_adj<<<BN * (NN / ROWS), 256, 0, stream>>>(out_phi, out_eta, adj);
}